// Round 17
// baseline (5670.724 us; speedup 1.0000x reference)
//
#include <hip/hip_runtime.h>
#include <cstdint>
#include <cstddef>

#define BATCH   8
#define NPTS    16384
#define CFEAT   64
#define NPOINT  2048
#define NSAMPLE 32
#define DIN     124
#define D1      128
#define D2      128
#define D3      256
#define LN_EPS  1e-5f

#define NFPS      8
#define NBLOCKS   256
#define KNN_ITEMS 128                   // 128 centroids per item (16 waves x 8)
#define MLP_ITEMS 2048                  // 8 centroids per item
#define TOT_ITEMS (KNN_ITEMS + MLP_ITEMS)

#define SB_BYTES   19872                // per-mlp-sub-block LDS region
#define SMEM_BYTES (8 * SB_BYTES)       // 158976 <= 160 KiB -> 1 block/CU

// control block layout (byte offsets; every sync word on its OWN 64B line)
#define CTL_QHEAD   0
#define CTL_PROG    1024    // prog[b]  at 1024 + b*256
#define CTL_KCNT    4096    // kcnt[k]  at 4096 + k*64
#define CTL_KFLAG   16384   // kflag[k] at 16384 + k*64
#define CTL_BYTES   32768

#define PAIRS8(F) F(0) F(1) F(2) F(3) F(4) F(5) F(6) F(7)
#define PTS16(F) F(0) F(1) F(2) F(3) F(4) F(5) F(6) F(7) \
                 F(8) F(9) F(10) F(11) F(12) F(13) F(14) F(15)

// packed-FP32 helpers (VOP3P dual-issue; per-component IEEE _rn rounding,
// identical to scalar v_add_f32/v_mul_f32 -> bit-exact vs reference)
typedef float v2f __attribute__((ext_vector_type(2)));
static __device__ __forceinline__ v2f pk_add2(v2f a, v2f b) {
  v2f r; asm("v_pk_add_f32 %0, %1, %2" : "=v"(r) : "v"(a), "v"(b)); return r;
}
static __device__ __forceinline__ v2f pk_mul2(v2f a, v2f b) {
  v2f r; asm("v_pk_mul_f32 %0, %1, %2" : "=v"(r) : "v"(a), "v"(b)); return r;
}

// ---------------------------------------------------------------------------
// Fused producer/consumer kernel (r17 = r16 + packed-f32 fps math,
// publish cadence back to every 16 steps).
//  - blocks 0..7: FPS. Inner loop now computes distances 2 points per
//    packed register (v_pk_add/v_pk_mul): ~40% fewer wave-instructions.
//    sub(p,c) expressed as add(p, -c) -- bit-exact (IEEE negate = sign flip).
//    fmin/argmax/tie-break unchanged (bit-identical selections).
//  - blocks 8..255: workers; FIFO queue: 128 knn items then 2048 mlp items.
// All selection math bit-identical to r13..r16 (passing, absmax 0.0156).
// ---------------------------------------------------------------------------
__attribute__((amdgpu_waves_per_eu(4, 4)))
__global__ __launch_bounds__(1024) void fused_kernel(
    const float* __restrict__ xyz, const float* __restrict__ features,
    const float* __restrict__ W1, const float* __restrict__ b1,
    const float* __restrict__ g1, const float* __restrict__ be1,
    const float* __restrict__ W2, const float* __restrict__ b2,
    const float* __restrict__ g2, const float* __restrict__ be2,
    const float* __restrict__ W3, const float* __restrict__ b3,
    int* __restrict__ knn_idx, unsigned char* __restrict__ ctl,
    float* __restrict__ new_xyz, float* __restrict__ out)
{
  __shared__ __align__(16) unsigned char smem[SMEM_BYTES];
  __shared__ unsigned s_item;
  const int t = threadIdx.x;

  unsigned* qhead = (unsigned*)(ctl + CTL_QHEAD);
#define PROG_AT(b)  ((int*)(ctl + CTL_PROG + (b) * 256))
#define KCNT_AT(k)  ((unsigned*)(ctl + CTL_KCNT + (k) * 64))
#define KFLAG_AT(k) ((unsigned*)(ctl + CTL_KFLAG + (k) * 64))

  // ========================= FPS role (blocks 0..7) =========================
  if (blockIdx.x < NFPS) {
    const int b = blockIdx.x;
    const float* X = xyz + (size_t)b * NPTS * 3;

    float4 (*s_mind4)[1024] = reinterpret_cast<float4(*)[1024]>(smem);
    float* wvv = (float*)(smem + 65536);
    unsigned long long* s_packed = (unsigned long long*)(smem + 65600);
    float* cbuf = (float*)(smem + 65616);

    // pair j holds points i=2j (lo) and i=2j+1 (hi); point i is global t+(i<<10)
#define DECLP(j) v2f pxp##j, pyp##j, pzp##j;
    PAIRS8(DECLP)
#undef DECLP
#define LOADP(j) { int ja = t + ((2*j) << 10), jb = t + ((2*j+1) << 10); \
    pxp##j = (v2f){X[3*ja+0], X[3*jb+0]};                               \
    pyp##j = (v2f){X[3*ja+1], X[3*jb+1]};                               \
    pzp##j = (v2f){X[3*ja+2], X[3*jb+2]}; }
    PAIRS8(LOADP)
#undef LOADP
    s_mind4[0][t] = make_float4(1e10f, 1e10f, 1e10f, 1e10f);
    s_mind4[1][t] = make_float4(1e10f, 1e10f, 1e10f, 1e10f);
    s_mind4[2][t] = make_float4(1e10f, 1e10f, 1e10f, 1e10f);
    s_mind4[3][t] = make_float4(1e10f, 1e10f, 1e10f, 1e10f);

    if (t == 0) { cbuf[0] = X[0]; cbuf[1] = X[1]; cbuf[2] = X[2]; *s_packed = 0ull; }
    __syncthreads();

    for (int s = 0; s < NPOINT; ++s) {
      const float cx = cbuf[0], cy = cbuf[1], cz = cbuf[2];
      if (t == 0) {
        float* o = new_xyz + ((size_t)b * NPOINT + s) * 3;
        o[0] = cx; o[1] = cy; o[2] = cz;
        *s_packed = 0ull;
        if (((s + 1) & 15) == 0) {   // publish every 16 steps (incl. s=2047)
          __builtin_amdgcn_fence(__ATOMIC_RELEASE, "agent");
          __hip_atomic_store(PROG_AT(b), s + 1, __ATOMIC_RELAXED,
                             __HIP_MEMORY_SCOPE_AGENT);
        }
      }
      if (s == NPOINT - 1) break;

      // pin packed coords in VGPR pairs (blocks spill/remat)
      asm volatile("" : "+v"(pxp0), "+v"(pxp1), "+v"(pxp2), "+v"(pxp3),
                        "+v"(pxp4), "+v"(pxp5), "+v"(pxp6), "+v"(pxp7));
      asm volatile("" : "+v"(pyp0), "+v"(pyp1), "+v"(pyp2), "+v"(pyp3),
                        "+v"(pyp4), "+v"(pyp5), "+v"(pyp6), "+v"(pyp7));
      asm volatile("" : "+v"(pzp0), "+v"(pzp1), "+v"(pzp2), "+v"(pzp3),
                        "+v"(pzp4), "+v"(pzp5), "+v"(pzp6), "+v"(pzp7));

      // exact negation (sign flip); p - c == p + (-c) bit-exactly
      const v2f ncx = (v2f){-cx, -cx};
      const v2f ncy = (v2f){-cy, -cy};
      const v2f ncz = (v2f){-cz, -cz};

      float mybest = -1.0f;
#define DIST2(j) ({                                                      \
    v2f dx_ = pk_add2(pxp##j, ncx);                                      \
    v2f dy_ = pk_add2(pyp##j, ncy);                                      \
    v2f dz_ = pk_add2(pzp##j, ncz);                                      \
    pk_add2(pk_add2(pk_mul2(dx_, dx_), pk_mul2(dy_, dy_)),               \
            pk_mul2(dz_, dz_)); })
#define PACKSTEP(p, jA, jB) {                                            \
    v2f dA = DIST2(jA);                                                  \
    v2f dB = DIST2(jB);                                                  \
    float4 dv = s_mind4[p][t];                                           \
    dv.x = fminf(dv.x, dA.x);                                            \
    dv.y = fminf(dv.y, dA.y);                                            \
    dv.z = fminf(dv.z, dB.x);                                            \
    dv.w = fminf(dv.w, dB.y);                                            \
    s_mind4[p][t] = dv;                                                  \
    mybest = fmaxf(mybest, fmaxf(fmaxf(dv.x, dv.y), fmaxf(dv.z, dv.w))); }
      PACKSTEP(0, 0, 1)
      PACKSTEP(1, 2, 3)
      PACKSTEP(2, 4, 5)
      PACKSTEP(3, 6, 7)
#undef PACKSTEP
#undef DIST2

      float wmax = mybest;
#pragma unroll
      for (int off = 32; off >= 1; off >>= 1)
        wmax = fmaxf(wmax, __shfl_xor(wmax, off));
      if ((t & 63) == 0) wvv[t >> 6] = wmax;
      __syncthreads();   // B1

      float4 v0 = *(const float4*)&wvv[0];
      float4 v1 = *(const float4*)&wvv[4];
      float4 v2 = *(const float4*)&wvv[8];
      float4 v3 = *(const float4*)&wvv[12];
      float g = fmaxf(
          fmaxf(fmaxf(fmaxf(v0.x, v0.y), fmaxf(v0.z, v0.w)),
                fmaxf(fmaxf(v1.x, v1.y), fmaxf(v1.z, v1.w))),
          fmaxf(fmaxf(fmaxf(v2.x, v2.y), fmaxf(v2.z, v2.w)),
                fmaxf(fmaxf(v3.x, v3.y), fmaxf(v3.z, v3.w))));

      if (mybest == g) {
        int kk = 16;
#pragma unroll
        for (int p = 3; p >= 0; --p) {
          float4 dv = s_mind4[p][t];
          if (dv.w == g) kk = 4 * p + 3;
          if (dv.z == g) kk = 4 * p + 2;
          if (dv.y == g) kk = 4 * p + 1;
          if (dv.x == g) kk = 4 * p + 0;
        }
        unsigned idx = (unsigned)(t + (kk << 10));
        unsigned long long pk =
            ((unsigned long long)__float_as_uint(g) << 32) | (unsigned)(~idx);
        atomicMax(s_packed, pk);
      }
      __syncthreads();   // B2

      unsigned long long gp = *s_packed;
      int widx = (int)(~(unsigned)(gp & 0xffffffffull)) & 0x3fff;
      if (t == (widx & 1023)) {
        int c = widx >> 10;         // point index 0..15
        int jp = c >> 1, hi = c & 1;
#define OWNP(jj) if (jp == jj) {                      \
    cbuf[0] = hi ? pxp##jj.y : pxp##jj.x;             \
    cbuf[1] = hi ? pyp##jj.y : pyp##jj.x;             \
    cbuf[2] = hi ? pzp##jj.y : pzp##jj.x; }
        PAIRS8(OWNP)
#undef OWNP
      }
      __syncthreads();   // B3
    }
    return;
  }

  // ========================= worker role (blocks 8..255) ====================
  for (;;) {
    __syncthreads();
    if (t == 0)
      s_item = __hip_atomic_fetch_add(qhead, 1u, __ATOMIC_RELAXED,
                                      __HIP_MEMORY_SCOPE_AGENT);
    __syncthreads();
    unsigned item = s_item;
    if (item >= TOT_ITEMS) return;

    if (item < KNN_ITEMS) {
      // ---------------- knn item: 128 centroids, 16 waves x 8 --------------
      const int k = (int)item;
      const int b = k >> 4;                    // 16 chunks per batch
      const int chunk = k & 15;
      const int lane = t & 63;
      const int wid  = t >> 6;
      const int gidbase = b * NPOINT + chunk * 128 + wid * 8;
      const int need = chunk * 128 + wid * 8 + 8;
      const float* X = xyz + (size_t)b * NPTS * 3;

      if (lane == 0) {
        while (__hip_atomic_load(PROG_AT(b), __ATOMIC_RELAXED,
                                 __HIP_MEMORY_SCOPE_AGENT) < need)
          __builtin_amdgcn_s_sleep(64);
      }
      __builtin_amdgcn_fence(__ATOMIC_ACQUIRE, "agent");

      float cx[8], cy[8], cz[8];
#pragma unroll
      for (int c = 0; c < 8; ++c) {
        const float* p = new_xyz + (size_t)(gidbase + c) * 3;
        cx[c] = p[0]; cy[c] = p[1]; cz[c] = p[2];
      }
      float qd[8]; int qi[8]; float T[8];
#pragma unroll
      for (int c = 0; c < 8; ++c) { qd[c] = 3.4e38f; qi[c] = 0; T[c] = 3.4e38f; }

      for (int base = 0; base < NPTS; base += 64) {
        const int j = base + lane;
        const float x = X[3 * j + 0];
        const float y = X[3 * j + 1];
        const float z = X[3 * j + 2];
#pragma unroll
        for (int c = 0; c < 8; ++c) {
          float dx = __fsub_rn(x, cx[c]);
          float dy = __fsub_rn(y, cy[c]);
          float dz = __fsub_rn(z, cz[c]);
          float v  = __fadd_rn(__fadd_rn(__fmul_rn(dx, dx), __fmul_rn(dy, dy)),
                               __fmul_rn(dz, dz));
          unsigned long long m = __ballot(v < T[c]);
          while (m) {
            int bit = __ffsll(m) - 1;
            m &= m - 1;
            float vb = __shfl(v, bit);
            if (vb < T[c]) {
              int   jb = base + bit;
              float du = __shfl_up(qd[c], 1);
              int   iu = __shfl_up(qi[c], 1);
              bool c2 = (lane > 0) && (vb < du);
              bool c1 = vb < qd[c];
              qd[c] = c2 ? du : (c1 ? vb : qd[c]);
              qi[c] = c2 ? iu : (c1 ? jb : qi[c]);
              T[c] = __shfl(qd[c], 31);
            }
          }
        }
      }
#pragma unroll
      for (int c = 0; c < 8; ++c) {
        if (lane < 32) knn_idx[(size_t)(gidbase + c) * NSAMPLE + lane] = qi[c];
      }
      __builtin_amdgcn_fence(__ATOMIC_RELEASE, "agent");
      if (lane == 0) {
        unsigned d = __hip_atomic_fetch_add(KCNT_AT(k), 1u, __ATOMIC_ACQ_REL,
                                            __HIP_MEMORY_SCOPE_AGENT);
        if (d == 15u)
          __hip_atomic_store(KFLAG_AT(k), 1u, __ATOMIC_RELEASE,
                             __HIP_MEMORY_SCOPE_AGENT);
      }
    } else {
      // ---------------- mlp item: 8 centroids, 8 x 128-thr sub-blocks ------
      const int m = (int)(item - KNN_ITEMS);
      const int gbase = m << 3;
      const int b = gbase / NPOINT;
      const int sb = t >> 7;
      const int t127 = t & 127;
      const int g = gbase + sb;

      if (t == 0) {
        while (__hip_atomic_load(KFLAG_AT(m >> 4), __ATOMIC_RELAXED,
                                 __HIP_MEMORY_SCOPE_AGENT) == 0u)
          __builtin_amdgcn_s_sleep(64);
      }
      __syncthreads();
      __builtin_amdgcn_fence(__ATOMIC_ACQUIRE, "agent");

      unsigned char* base_ = smem + sb * SB_BYTES;
      float* bufT = (float*)base_;                         // 128*36 floats
      float (*red)[4][2] = (float(*)[4][2])(base_ + 18432);
      float (*lnp)[2]    = (float(*)[2])(base_ + 19456);
      int*   ki          = (int*)(base_ + 19712);
      float* cen         = (float*)(base_ + 19840);

      if (t127 < 32) ki[t127] = knn_idx[(size_t)g * NSAMPLE + t127];
      if (t127 < 3)  cen[t127] = new_xyz[(size_t)g * 3 + t127];
      __syncthreads();

      {
        int r = t127 & 31, cs = (t127 >> 5) << 4;
        const float* frow = features + ((size_t)b * NPTS + ki[r]) * CFEAT + cs;
#pragma unroll
        for (int u = 0; u < 4; ++u) {
          float4 f = *(const float4*)(frow + 4 * u);
          bufT[(cs + 4 * u + 0) * 36 + r] = f.x;
          bufT[(cs + 4 * u + 1) * 36 + r] = f.y;
          bufT[(cs + 4 * u + 2) * 36 + r] = f.z;
          bufT[(cs + 4 * u + 3) * 36 + r] = f.w;
        }
      }
      if (t127 < 32) {
        const float* p = xyz + ((size_t)b * NPTS + ki[t127]) * 3;
        float rx = p[0] - cen[0];
        float ry = p[1] - cen[1];
        float rz = p[2] - cen[2];
#pragma unroll
        for (int l = 0; l < 10; ++l) {
          float sc = (float)(1 << l);
          float ax = rx * sc, ay = ry * sc, az = rz * sc;
          int bbi = (64 + l * 6) * 36 + t127;
          bufT[bbi + 0 * 36] = __sinf(ax);
          bufT[bbi + 1 * 36] = __sinf(ay);
          bufT[bbi + 2 * 36] = __sinf(az);
          bufT[bbi + 3 * 36] = __cosf(ax);
          bufT[bbi + 4 * 36] = __cosf(ay);
          bufT[bbi + 5 * 36] = __cosf(az);
        }
      }
      __syncthreads();

      float acc[32];
      // ---- layer 1 ----
      {
        float bias = b1[t127];
#pragma unroll
        for (int r = 0; r < 32; ++r) acc[r] = bias;
        for (int i = 0; i < DIN; ++i) {
          float w = W1[i * D1 + t127];
          const float* hr = &bufT[i * 36];
#pragma unroll
          for (int r = 0; r < 32; ++r) acc[r] = fmaf(hr[r], w, acc[r]);
        }
      }
      {
        __syncthreads();
#pragma unroll
        for (int r = 0; r < 32; ++r) bufT[t127 * 36 + r] = acc[r];
        __syncthreads();
        {
          int r = t127 & 31, seg = t127 >> 5;
          float s = 0.f, ss = 0.f;
#pragma unroll
          for (int u = 0; u < 32; ++u) {
            float v = bufT[(seg * 32 + u) * 36 + r];
            s += v; ss = fmaf(v, v, ss);
          }
          red[r][seg][0] = s; red[r][seg][1] = ss;
        }
        __syncthreads();
        if (t127 < 32) {
          float s  = red[t127][0][0] + red[t127][1][0] + red[t127][2][0] + red[t127][3][0];
          float ss = red[t127][0][1] + red[t127][1][1] + red[t127][2][1] + red[t127][3][1];
          float mm = s * (1.0f / D1);
          float var = ss * (1.0f / D1) - mm * mm;
          lnp[t127][0] = mm;
          lnp[t127][1] = rsqrtf(var + LN_EPS);
        }
        __syncthreads();
        float gg = g1[t127], bb = be1[t127];
#pragma unroll
        for (int r = 0; r < 32; ++r) {
          float v = (acc[r] - lnp[r][0]) * lnp[r][1];
          v = fmaf(v, gg, bb);
          bufT[t127 * 36 + r] = fmaxf(v, 0.f);
        }
        __syncthreads();
      }
      // ---- layer 2 ----
      {
        float bias = b2[t127];
#pragma unroll
        for (int r = 0; r < 32; ++r) acc[r] = bias;
        for (int i = 0; i < D1; ++i) {
          float w = W2[i * D2 + t127];
          const float* hr = &bufT[i * 36];
#pragma unroll
          for (int r = 0; r < 32; ++r) acc[r] = fmaf(hr[r], w, acc[r]);
        }
      }
      {
        __syncthreads();
#pragma unroll
        for (int r = 0; r < 32; ++r) bufT[t127 * 36 + r] = acc[r];
        __syncthreads();
        {
          int r = t127 & 31, seg = t127 >> 5;
          float s = 0.f, ss = 0.f;
#pragma unroll
          for (int u = 0; u < 32; ++u) {
            float v = bufT[(seg * 32 + u) * 36 + r];
            s += v; ss = fmaf(v, v, ss);
          }
          red[r][seg][0] = s; red[r][seg][1] = ss;
        }
        __syncthreads();
        if (t127 < 32) {
          float s  = red[t127][0][0] + red[t127][1][0] + red[t127][2][0] + red[t127][3][0];
          float ss = red[t127][0][1] + red[t127][1][1] + red[t127][2][1] + red[t127][3][1];
          float mm = s * (1.0f / D2);
          float var = ss * (1.0f / D2) - mm * mm;
          lnp[t127][0] = mm;
          lnp[t127][1] = rsqrtf(var + LN_EPS);
        }
        __syncthreads();
        float gg = g2[t127], bb = be2[t127];
#pragma unroll
        for (int r = 0; r < 32; ++r) {
          float v = (acc[r] - lnp[r][0]) * lnp[r][1];
          v = fmaf(v, gg, bb);
          bufT[t127 * 36 + r] = fmaxf(v, 0.f);
        }
        __syncthreads();
      }
      // ---- layer 3 + max over k: two 32-reg passes ----
      float* of = out + (size_t)g * D3;
#pragma unroll 1
      for (int half = 0; half < 2; ++half) {
        int col = t127 + (half << 7);
        float a[32];
        float bias = b3[col];
#pragma unroll
        for (int r = 0; r < 32; ++r) a[r] = bias;
        for (int i = 0; i < D2; ++i) {
          float w = W3[i * D3 + col];
          const float* hr = &bufT[i * 36];
#pragma unroll
          for (int r = 0; r < 32; ++r) a[r] = fmaf(hr[r], w, a[r]);
        }
        float m0 = a[0];
#pragma unroll
        for (int r = 1; r < 32; ++r) m0 = fmaxf(m0, a[r]);
        of[col] = m0;
      }
      __syncthreads();   // sub-blocks done before LDS reuse by next item
    }
  }
#undef PROG_AT
#undef KCNT_AT
#undef KFLAG_AT
}

// ---------------------------------------------------------------------------
extern "C" void kernel_launch(void* const* d_in, const int* in_sizes, int n_in,
                              void* d_out, int out_size, void* d_ws, size_t ws_size,
                              hipStream_t stream) {
  const float* xyz      = (const float*)d_in[0];
  const float* features = (const float*)d_in[1];
  const float* W1  = (const float*)d_in[2];
  const float* b1  = (const float*)d_in[3];
  const float* g1  = (const float*)d_in[4];
  const float* be1 = (const float*)d_in[5];
  const float* W2  = (const float*)d_in[6];
  const float* b2  = (const float*)d_in[7];
  const float* g2  = (const float*)d_in[8];
  const float* be2 = (const float*)d_in[9];
  const float* W3  = (const float*)d_in[10];
  const float* b3  = (const float*)d_in[11];

  float* new_xyz  = (float*)d_out;
  float* new_feat = (float*)d_out + (size_t)BATCH * NPOINT * 3;

  int* knn_idx = (int*)d_ws;                                    // 2 MB
  unsigned char* ctl = (unsigned char*)d_ws +
                       (size_t)BATCH * NPOINT * NSAMPLE * 4;

  hipMemsetAsync(ctl, 0, CTL_BYTES, stream);
  fused_kernel<<<dim3(NBLOCKS), dim3(1024), 0, stream>>>(
      xyz, features, W1, b1, g1, be1, W2, b2, g2, be2, W3, b3,
      knn_idx, ctl, new_xyz, new_feat);
}

// Round 18
// 4833.762 us; speedup vs baseline: 1.1731x; 1.1731x over previous
//
#include <hip/hip_runtime.h>
#include <cstdint>
#include <cstddef>

#define BATCH   8
#define NPTS    16384
#define CFEAT   64
#define NPOINT  2048
#define NSAMPLE 32
#define DIN     124
#define D1      128
#define D2      128
#define D3      256
#define LN_EPS  1e-5f

#define NFPS      8
#define NBLOCKS   256
#define KNN_ITEMS 128                   // 128 centroids per item (16 waves x 8)
#define MLP_ITEMS 2048                  // 8 centroids per item
#define TOT_ITEMS (KNN_ITEMS + MLP_ITEMS)

#define SB_BYTES   19872                // per-mlp-sub-block LDS region
#define SMEM_BYTES (8 * SB_BYTES)       // 158976 <= 160 KiB -> 1 block/CU

// control block layout (byte offsets; every sync word on its OWN 64B line)
#define CTL_QHEAD   0
#define CTL_PROG    1024    // prog[b]  at 1024 + b*256
#define CTL_KCNT    4096    // kcnt[k]  at 4096 + k*64
#define CTL_KFLAG   16384   // kflag[k] at 16384 + k*64
#define CTL_BYTES   32768

#define PTS16(F) F(0) F(1) F(2) F(3) F(4) F(5) F(6) F(7) \
                 F(8) F(9) F(10) F(11) F(12) F(13) F(14) F(15)

// sorted point storage (module BSS; r8-proven pattern)
__device__ float          g_sx[BATCH][NPTS];
__device__ float          g_sy[BATCH][NPTS];
__device__ float          g_sz[BATCH][NPTS];
__device__ unsigned short g_so[BATCH][NPTS];   // original index

// ---------------------------------------------------------------------------
// Fused producer/consumer kernel (r18 = r14 structure + Morton-sorted FPS
// with wave-level bbox skip).
// FPS blocks 0..7: points counting-sorted by Morton cell (setup, once;
// r8-proven sort). Thread t owns sorted [t*16,t*16+16); wave owns a compact
// spatial block. Per step, ONE wave-uniform test (dlb2(c, wave bbox) vs
// cached wave max mindist * 1.0001) skips the whole 192-inst update when no
// dist can change -- values bit-identical by monotonicity. Argmax/tie-break
// on ORIGINAL index via packed u64 (valbits<<32 | (~orig&0x3FFF)<<14 | spos).
// Workers (blocks 8..255): FIFO queue, 128 knn items then 2048 mlp items
// (byte-identical to r14/r15/r16). Exact reference f32 math everywhere.
// ---------------------------------------------------------------------------
__attribute__((amdgpu_waves_per_eu(4, 4)))
__global__ __launch_bounds__(1024) void fused_kernel(
    const float* __restrict__ xyz, const float* __restrict__ features,
    const float* __restrict__ W1, const float* __restrict__ b1,
    const float* __restrict__ g1, const float* __restrict__ be1,
    const float* __restrict__ W2, const float* __restrict__ b2,
    const float* __restrict__ g2, const float* __restrict__ be2,
    const float* __restrict__ W3, const float* __restrict__ b3,
    int* __restrict__ knn_idx, unsigned char* __restrict__ ctl,
    float* __restrict__ new_xyz, float* __restrict__ out)
{
  __shared__ __align__(16) unsigned char smem[SMEM_BYTES];
  __shared__ unsigned s_item;
  const int t = threadIdx.x;

  unsigned* qhead = (unsigned*)(ctl + CTL_QHEAD);
#define PROG_AT(b)  ((int*)(ctl + CTL_PROG + (b) * 256))
#define KCNT_AT(k)  ((unsigned*)(ctl + CTL_KCNT + (k) * 64))
#define KFLAG_AT(k) ((unsigned*)(ctl + CTL_KFLAG + (k) * 64))

  // ========================= FPS role (blocks 0..7) =========================
  if (blockIdx.x < NFPS) {
    const int b = blockIdx.x;
    const float* X = xyz + (size_t)b * NPTS * 3;

    float4 (*s_mind4)[1024] = reinterpret_cast<float4(*)[1024]>(smem);
    unsigned short* s_oidx  = (unsigned short*)(smem + 65536);   // [k<<10 | t]
    float* wvv              = (float*)(smem + 98304);
    unsigned long long* s_packed = (unsigned long long*)(smem + 98368);
    float* cbuf             = (float*)(smem + 98432);
    float (*wbb)[6]         = (float(*)[6])(smem + 98496);       // per-wave bbox
    float* gpar             = (float*)(smem + 98944);            // lo xyz, iscale xyz
    unsigned* cstart        = (unsigned*)(smem + 99008);         // [513]
    unsigned* ccur          = (unsigned*)(smem + 101120);        // [512]
    float (*redbuf)[6]      = (float(*)[6])(smem + 103168);

#define DECLP(i) float px##i, py##i, pz##i;
    PTS16(DECLP)
#undef DECLP
    // ---- load original strided layout ----
#define LOADP(i) { int j = t + (i << 10);  \
    px##i = X[3 * j + 0];                  \
    py##i = X[3 * j + 1];                  \
    pz##i = X[3 * j + 2]; }
    PTS16(LOADP)
#undef LOADP

    // ---- global bbox reduce (for cell grid) ----
    {
      float mnx = px0, mxx = px0, mny = py0, mxy = py0, mnz = pz0, mxz = pz0;
#define BB(i) { mnx = fminf(mnx, px##i); mxx = fmaxf(mxx, px##i);  \
                mny = fminf(mny, py##i); mxy = fmaxf(mxy, py##i);  \
                mnz = fminf(mnz, pz##i); mxz = fmaxf(mxz, pz##i); }
      PTS16(BB)
#undef BB
#pragma unroll
      for (int off = 32; off >= 1; off >>= 1) {
        mnx = fminf(mnx, __shfl_xor(mnx, off)); mxx = fmaxf(mxx, __shfl_xor(mxx, off));
        mny = fminf(mny, __shfl_xor(mny, off)); mxy = fmaxf(mxy, __shfl_xor(mxy, off));
        mnz = fminf(mnz, __shfl_xor(mnz, off)); mxz = fmaxf(mxz, __shfl_xor(mxz, off));
      }
      if ((t & 63) == 0) {
        int w = t >> 6;
        redbuf[w][0] = mnx; redbuf[w][1] = mxx; redbuf[w][2] = mny;
        redbuf[w][3] = mxy; redbuf[w][4] = mnz; redbuf[w][5] = mxz;
      }
      if (t < 513) cstart[t] = 0;
      __syncthreads();
      if (t == 0) {
        float a0 = redbuf[0][0], a1 = redbuf[0][1], a2 = redbuf[0][2];
        float a3 = redbuf[0][3], a4 = redbuf[0][4], a5 = redbuf[0][5];
        for (int w = 1; w < 16; ++w) {
          a0 = fminf(a0, redbuf[w][0]); a1 = fmaxf(a1, redbuf[w][1]);
          a2 = fminf(a2, redbuf[w][2]); a3 = fmaxf(a3, redbuf[w][3]);
          a4 = fminf(a4, redbuf[w][4]); a5 = fmaxf(a5, redbuf[w][5]);
        }
        float rx = a1 - a0, ry = a3 - a2, rz = a5 - a4;
        gpar[0] = a0; gpar[1] = a2; gpar[2] = a4;
        gpar[3] = (rx > 1e-20f) ? 8.0f / rx : 0.f;
        gpar[4] = (ry > 1e-20f) ? 8.0f / ry : 0.f;
        gpar[5] = (rz > 1e-20f) ? 8.0f / rz : 0.f;
        cbuf[0] = X[0]; cbuf[1] = X[1]; cbuf[2] = X[2];
        *s_packed = 0ull;
      }
      __syncthreads();
    }

    // Morton cell id (3x3-bit interleave)
#define CELLM(x, y, z) ({                                              \
    int ix_ = (int)((x - gpar[0]) * gpar[3]);                          \
    int iy_ = (int)((y - gpar[1]) * gpar[4]);                          \
    int iz_ = (int)((z - gpar[2]) * gpar[5]);                          \
    ix_ = ix_ < 0 ? 0 : (ix_ > 7 ? 7 : ix_);                           \
    iy_ = iy_ < 0 ? 0 : (iy_ > 7 ? 7 : iy_);                           \
    iz_ = iz_ < 0 ? 0 : (iz_ > 7 ? 7 : iz_);                           \
    (((ix_ & 1) | ((ix_ & 2) << 2) | ((ix_ & 4) << 4))                 \
     | (((iy_ & 1) | ((iy_ & 2) << 2) | ((iy_ & 4) << 4)) << 1)        \
     | (((iz_ & 1) | ((iz_ & 2) << 2) | ((iz_ & 4) << 4)) << 2)); })

    // ---- histogram ----
#define CIDK(i) { int m_ = CELLM(px##i, py##i, pz##i); \
    atomicAdd(&cstart[m_ + 1], 1u); }
    PTS16(CIDK)
#undef CIDK
    __syncthreads();

    // ---- prefix scan (wave 0; r8-proven) ----
    if (t < 64) {
      unsigned v[8], p[8];
      unsigned run = 0;
#pragma unroll
      for (int j = 0; j < 8; ++j) { v[j] = cstart[t * 8 + 1 + j]; run += v[j]; p[j] = run; }
      unsigned tot = run;
#pragma unroll
      for (int off = 1; off < 64; off <<= 1) {
        unsigned u = __shfl_up(run, off);
        if ((t & 63) >= off) run += u;
      }
      unsigned excl = run - tot;
      if (t == 0) cstart[0] = 0;
#pragma unroll
      for (int j = 0; j < 8; ++j) cstart[t * 8 + 1 + j] = excl + p[j];
    }
    __syncthreads();
    if (t < 512) ccur[t] = cstart[t];
    __syncthreads();

    // ---- scatter to global (sorted SoA) ----
#define SCATK(i) { int j = t + (i << 10);                              \
    int m_ = CELLM(px##i, py##i, pz##i);                               \
    unsigned dst = atomicAdd(&ccur[m_], 1u);                           \
    g_sx[b][dst] = px##i; g_sy[b][dst] = py##i; g_sz[b][dst] = pz##i;  \
    g_so[b][dst] = (unsigned short)j; }
    PTS16(SCATK)
#undef SCATK
#undef CELLM
    __syncthreads();   // vmcnt drained before barrier by compiler

    // ---- reload sorted (thread t owns [t*16, t*16+16)), thread bbox ----
    float tlx = 1e30f, thx = -1e30f, tly = 1e30f, thy = -1e30f,
          tlz = 1e30f, thz = -1e30f;
#define RELK(i) { int p_ = (t << 4) + i;                               \
    px##i = g_sx[b][p_]; py##i = g_sy[b][p_]; pz##i = g_sz[b][p_];     \
    s_oidx[(i << 10) + t] = g_so[b][p_];                               \
    tlx = fminf(tlx, px##i); thx = fmaxf(thx, px##i);                  \
    tly = fminf(tly, py##i); thy = fmaxf(thy, py##i);                  \
    tlz = fminf(tlz, pz##i); thz = fmaxf(thz, pz##i); }
    PTS16(RELK)
#undef RELK
    s_mind4[0][t] = make_float4(1e10f, 1e10f, 1e10f, 1e10f);
    s_mind4[1][t] = make_float4(1e10f, 1e10f, 1e10f, 1e10f);
    s_mind4[2][t] = make_float4(1e10f, 1e10f, 1e10f, 1e10f);
    s_mind4[3][t] = make_float4(1e10f, 1e10f, 1e10f, 1e10f);

    // ---- wave bbox ----
#pragma unroll
    for (int off = 32; off >= 1; off >>= 1) {
      tlx = fminf(tlx, __shfl_xor(tlx, off)); thx = fmaxf(thx, __shfl_xor(thx, off));
      tly = fminf(tly, __shfl_xor(tly, off)); thy = fmaxf(thy, __shfl_xor(thy, off));
      tlz = fminf(tlz, __shfl_xor(tlz, off)); thz = fmaxf(thz, __shfl_xor(thz, off));
    }
    if ((t & 63) == 0) {
      int w = t >> 6;
      wbb[w][0] = tlx; wbb[w][1] = thx; wbb[w][2] = tly;
      wbb[w][3] = thy; wbb[w][4] = tlz; wbb[w][5] = thz;
    }

    float mybest = -1.0f;       // per-thread max of own dists (valid when set)
    float wvmax  = 1e10f;       // wave's cached max mindist (uniform)
    int   far    = 0;
    __syncthreads();

    // ======================= main FPS loop =======================
    for (int s = 0; s < NPOINT; ++s) {
      const float cx = cbuf[0], cy = cbuf[1], cz = cbuf[2];
      if (t == 0) {
        fps_idx_write:;
        // (label unused; kept structure flat)
        ((int*)0 == (int*)0);
      }
      if (t == 0) {
        // outputs + per-step reset + periodic publish
        int* fi = (int*)knn_idx;  // placeholder no-op to keep scopes clean
        (void)fi;
      }
      if (t == 0) {
        // fps_idx lives in d_ws via knn_idx? no -- separate pointer below
      }
      // NOTE: actual output writes below (kept single block for clarity)
      if (t == 0) {
        float* o = new_xyz + ((size_t)b * NPOINT + s) * 3;
        o[0] = cx; o[1] = cy; o[2] = cz;
        *s_packed = 0ull;
        if (((s + 1) & 15) == 0) {   // publish every 16 steps (incl. s=2047)
          __builtin_amdgcn_fence(__ATOMIC_RELEASE, "agent");
          __hip_atomic_store(PROG_AT(b), s + 1, __ATOMIC_RELAXED,
                             __HIP_MEMORY_SCOPE_AGENT);
        }
      }
      if (s == NPOINT - 1) break;

      // pin coords (blocks spill/remat)
      asm volatile("" : "+v"(px0), "+v"(px1), "+v"(px2), "+v"(px3),
                        "+v"(px4), "+v"(px5), "+v"(px6), "+v"(px7),
                        "+v"(px8), "+v"(px9), "+v"(px10), "+v"(px11),
                        "+v"(px12), "+v"(px13), "+v"(px14), "+v"(px15));
      asm volatile("" : "+v"(py0), "+v"(py1), "+v"(py2), "+v"(py3),
                        "+v"(py4), "+v"(py5), "+v"(py6), "+v"(py7),
                        "+v"(py8), "+v"(py9), "+v"(py10), "+v"(py11),
                        "+v"(py12), "+v"(py13), "+v"(py14), "+v"(py15));
      asm volatile("" : "+v"(pz0), "+v"(pz1), "+v"(pz2), "+v"(pz3),
                        "+v"(pz4), "+v"(pz5), "+v"(pz6), "+v"(pz7),
                        "+v"(pz8), "+v"(pz9), "+v"(pz10), "+v"(pz11),
                        "+v"(pz12), "+v"(pz13), "+v"(pz14), "+v"(pz15));

      // ---- wave-uniform skip test ----
      {
        const int w = t >> 6;
        float lox = wbb[w][0], hix = wbb[w][1];
        float loy = wbb[w][2], hiy = wbb[w][3];
        float loz = wbb[w][4], hiz = wbb[w][5];
        float ddx = fmaxf(fmaxf(lox - cx, cx - hix), 0.f);
        float ddy = fmaxf(fmaxf(loy - cy, cy - hiy), 0.f);
        float ddz = fmaxf(fmaxf(loz - cz, cz - hiz), 0.f);
        float dlb2 = ddx * ddx + ddy * ddy + ddz * ddz;
        if (dlb2 < wvmax * 1.0001f) {
          // dirty: full exact update (r14 core)
          mybest = -1.0f;
#define DIST(i) ({                                                       \
    float dx_ = __fsub_rn(px##i, cx);                                    \
    float dy_ = __fsub_rn(py##i, cy);                                    \
    float dz_ = __fsub_rn(pz##i, cz);                                    \
    __fadd_rn(__fadd_rn(__fmul_rn(dx_, dx_), __fmul_rn(dy_, dy_)),       \
              __fmul_rn(dz_, dz_)); })
#define PACKSTEP(p, i0, i1, i2, i3) {                                    \
    float4 dv = s_mind4[p][t];                                           \
    dv.x = fminf(dv.x, DIST(i0));                                        \
    dv.y = fminf(dv.y, DIST(i1));                                        \
    dv.z = fminf(dv.z, DIST(i2));                                        \
    dv.w = fminf(dv.w, DIST(i3));                                        \
    s_mind4[p][t] = dv;                                                  \
    mybest = fmaxf(mybest, fmaxf(fmaxf(dv.x, dv.y), fmaxf(dv.z, dv.w))); }
          PACKSTEP(0, 0, 1, 2, 3)
          PACKSTEP(1, 4, 5, 6, 7)
          PACKSTEP(2, 8, 9, 10, 11)
          PACKSTEP(3, 12, 13, 14, 15)
#undef PACKSTEP
#undef DIST
          float wmax = mybest;
#pragma unroll
          for (int off = 32; off >= 1; off >>= 1)
            wmax = fmaxf(wmax, __shfl_xor(wmax, off));
          wvmax = wmax;
          if ((t & 63) == 0) wvv[w] = wmax;
        }
      }
      __syncthreads();   // B1

      // stage 2 (redundant, f32): 4x b128 broadcast + max tree
      float4 v0 = *(const float4*)&wvv[0];
      float4 v1 = *(const float4*)&wvv[4];
      float4 v2 = *(const float4*)&wvv[8];
      float4 v3 = *(const float4*)&wvv[12];
      float g = fmaxf(
          fmaxf(fmaxf(fmaxf(v0.x, v0.y), fmaxf(v0.z, v0.w)),
                fmaxf(fmaxf(v1.x, v1.y), fmaxf(v1.z, v1.w))),
          fmaxf(fmaxf(fmaxf(v2.x, v2.y), fmaxf(v2.z, v2.w)),
                fmaxf(fmaxf(v3.x, v3.y), fmaxf(v3.z, v3.w))));

      // winners (bit-exact; rare): pick smallest ORIGINAL index in-thread,
      // then u64 atomicMax resolves cross-thread (value desc, orig asc)
      if (mybest == g) {
        unsigned bo = 0xFFFFu; int bk = 0;
#pragma unroll
        for (int p = 0; p < 4; ++p) {
          float4 dv = s_mind4[p][t];
          { unsigned o = s_oidx[((4 * p + 0) << 10) + t];
            if (dv.x == g && o < bo) { bo = o; bk = 4 * p + 0; } }
          { unsigned o = s_oidx[((4 * p + 1) << 10) + t];
            if (dv.y == g && o < bo) { bo = o; bk = 4 * p + 1; } }
          { unsigned o = s_oidx[((4 * p + 2) << 10) + t];
            if (dv.z == g && o < bo) { bo = o; bk = 4 * p + 2; } }
          { unsigned o = s_oidx[((4 * p + 3) << 10) + t];
            if (dv.w == g && o < bo) { bo = o; bk = 4 * p + 3; } }
        }
        unsigned payload = ((~bo & 0x3FFFu) << 14) | (unsigned)((t << 4) | bk);
        unsigned long long pk =
            ((unsigned long long)__float_as_uint(g) << 32) | payload;
        atomicMax(s_packed, pk);
      }
      __syncthreads();   // B2

      unsigned long long gp = *s_packed;
      unsigned pl = (unsigned)(gp & 0xffffffffull);
      far = (int)((~(pl >> 14)) & 0x3FFFu);          // ORIGINAL index
      int spos = (int)(pl & 0x3FFFu);                // sorted position
      if (t == (spos >> 4)) {
        int c = spos & 15;
#define OWNK(i) if (c == i) { cbuf[0] = px##i; cbuf[1] = py##i; cbuf[2] = pz##i; }
        PTS16(OWNK)
#undef OWNK
      }
      __syncthreads();   // B3
    }
    // final fps index write for s = NPOINT-1 already handled in-loop via
    // new_xyz; fps indices were consumed only through new_xyz -- but knn
    // reads new_xyz only, so nothing else needed here.
    return;
  }

  // ========================= worker role (blocks 8..255) ====================
  for (;;) {
    __syncthreads();
    if (t == 0)
      s_item = __hip_atomic_fetch_add(qhead, 1u, __ATOMIC_RELAXED,
                                      __HIP_MEMORY_SCOPE_AGENT);
    __syncthreads();
    unsigned item = s_item;
    if (item >= TOT_ITEMS) return;

    if (item < KNN_ITEMS) {
      // ---------------- knn item: 128 centroids, 16 waves x 8 --------------
      const int k = (int)item;
      const int b = k >> 4;                    // 16 chunks per batch
      const int chunk = k & 15;
      const int lane = t & 63;
      const int wid  = t >> 6;
      const int gidbase = b * NPOINT + chunk * 128 + wid * 8;
      const int need = chunk * 128 + wid * 8 + 8;
      const float* X = xyz + (size_t)b * NPTS * 3;

      if (lane == 0) {
        while (__hip_atomic_load(PROG_AT(b), __ATOMIC_RELAXED,
                                 __HIP_MEMORY_SCOPE_AGENT) < need)
          __builtin_amdgcn_s_sleep(64);
      }
      __builtin_amdgcn_fence(__ATOMIC_ACQUIRE, "agent");

      float cx[8], cy[8], cz[8];
#pragma unroll
      for (int c = 0; c < 8; ++c) {
        const float* p = new_xyz + (size_t)(gidbase + c) * 3;
        cx[c] = p[0]; cy[c] = p[1]; cz[c] = p[2];
      }
      float qd[8]; int qi[8]; float T[8];
#pragma unroll
      for (int c = 0; c < 8; ++c) { qd[c] = 3.4e38f; qi[c] = 0; T[c] = 3.4e38f; }

      for (int base = 0; base < NPTS; base += 64) {
        const int j = base + lane;
        const float x = X[3 * j + 0];
        const float y = X[3 * j + 1];
        const float z = X[3 * j + 2];
#pragma unroll
        for (int c = 0; c < 8; ++c) {
          float dx = __fsub_rn(x, cx[c]);
          float dy = __fsub_rn(y, cy[c]);
          float dz = __fsub_rn(z, cz[c]);
          float v  = __fadd_rn(__fadd_rn(__fmul_rn(dx, dx), __fmul_rn(dy, dy)),
                               __fmul_rn(dz, dz));
          unsigned long long m = __ballot(v < T[c]);
          while (m) {
            int bit = __ffsll(m) - 1;
            m &= m - 1;
            float vb = __shfl(v, bit);
            if (vb < T[c]) {
              int   jb = base + bit;
              float du = __shfl_up(qd[c], 1);
              int   iu = __shfl_up(qi[c], 1);
              bool c2 = (lane > 0) && (vb < du);
              bool c1 = vb < qd[c];
              qd[c] = c2 ? du : (c1 ? vb : qd[c]);
              qi[c] = c2 ? iu : (c1 ? jb : qi[c]);
              T[c] = __shfl(qd[c], 31);
            }
          }
        }
      }
#pragma unroll
      for (int c = 0; c < 8; ++c) {
        if (lane < 32) knn_idx[(size_t)(gidbase + c) * NSAMPLE + lane] = qi[c];
      }
      __builtin_amdgcn_fence(__ATOMIC_RELEASE, "agent");
      if (lane == 0) {
        unsigned d = __hip_atomic_fetch_add(KCNT_AT(k), 1u, __ATOMIC_ACQ_REL,
                                            __HIP_MEMORY_SCOPE_AGENT);
        if (d == 15u)
          __hip_atomic_store(KFLAG_AT(k), 1u, __ATOMIC_RELEASE,
                             __HIP_MEMORY_SCOPE_AGENT);
      }
    } else {
      // ---------------- mlp item: 8 centroids, 8 x 128-thr sub-blocks ------
      const int m = (int)(item - KNN_ITEMS);
      const int gbase = m << 3;
      const int b = gbase / NPOINT;
      const int sb = t >> 7;
      const int t127 = t & 127;
      const int g = gbase + sb;

      if (t == 0) {
        while (__hip_atomic_load(KFLAG_AT(m >> 4), __ATOMIC_RELAXED,
                                 __HIP_MEMORY_SCOPE_AGENT) == 0u)
          __builtin_amdgcn_s_sleep(64);
      }
      __syncthreads();
      __builtin_amdgcn_fence(__ATOMIC_ACQUIRE, "agent");

      unsigned char* base_ = smem + sb * SB_BYTES;
      float* bufT = (float*)base_;                         // 128*36 floats
      float (*red)[4][2] = (float(*)[4][2])(base_ + 18432);
      float (*lnp)[2]    = (float(*)[2])(base_ + 19456);
      int*   ki          = (int*)(base_ + 19712);
      float* cen         = (float*)(base_ + 19840);

      if (t127 < 32) ki[t127] = knn_idx[(size_t)g * NSAMPLE + t127];
      if (t127 < 3)  cen[t127] = new_xyz[(size_t)g * 3 + t127];
      __syncthreads();

      {
        int r = t127 & 31, cs = (t127 >> 5) << 4;
        const float* frow = features + ((size_t)b * NPTS + ki[r]) * CFEAT + cs;
#pragma unroll
        for (int u = 0; u < 4; ++u) {
          float4 f = *(const float4*)(frow + 4 * u);
          bufT[(cs + 4 * u + 0) * 36 + r] = f.x;
          bufT[(cs + 4 * u + 1) * 36 + r] = f.y;
          bufT[(cs + 4 * u + 2) * 36 + r] = f.z;
          bufT[(cs + 4 * u + 3) * 36 + r] = f.w;
        }
      }
      if (t127 < 32) {
        const float* p = xyz + ((size_t)b * NPTS + ki[t127]) * 3;
        float rx = p[0] - cen[0];
        float ry = p[1] - cen[1];
        float rz = p[2] - cen[2];
#pragma unroll
        for (int l = 0; l < 10; ++l) {
          float sc = (float)(1 << l);
          float ax = rx * sc, ay = ry * sc, az = rz * sc;
          int bbi = (64 + l * 6) * 36 + t127;
          bufT[bbi + 0 * 36] = __sinf(ax);
          bufT[bbi + 1 * 36] = __sinf(ay);
          bufT[bbi + 2 * 36] = __sinf(az);
          bufT[bbi + 3 * 36] = __cosf(ax);
          bufT[bbi + 4 * 36] = __cosf(ay);
          bufT[bbi + 5 * 36] = __cosf(az);
        }
      }
      __syncthreads();

      float acc[32];
      // ---- layer 1 ----
      {
        float bias = b1[t127];
#pragma unroll
        for (int r = 0; r < 32; ++r) acc[r] = bias;
        for (int i = 0; i < DIN; ++i) {
          float w = W1[i * D1 + t127];
          const float* hr = &bufT[i * 36];
#pragma unroll
          for (int r = 0; r < 32; ++r) acc[r] = fmaf(hr[r], w, acc[r]);
        }
      }
      {
        __syncthreads();
#pragma unroll
        for (int r = 0; r < 32; ++r) bufT[t127 * 36 + r] = acc[r];
        __syncthreads();
        {
          int r = t127 & 31, seg = t127 >> 5;
          float s = 0.f, ss = 0.f;
#pragma unroll
          for (int u = 0; u < 32; ++u) {
            float v = bufT[(seg * 32 + u) * 36 + r];
            s += v; ss = fmaf(v, v, ss);
          }
          red[r][seg][0] = s; red[r][seg][1] = ss;
        }
        __syncthreads();
        if (t127 < 32) {
          float s  = red[t127][0][0] + red[t127][1][0] + red[t127][2][0] + red[t127][3][0];
          float ss = red[t127][0][1] + red[t127][1][1] + red[t127][2][1] + red[t127][3][1];
          float mm = s * (1.0f / D1);
          float var = ss * (1.0f / D1) - mm * mm;
          lnp[t127][0] = mm;
          lnp[t127][1] = rsqrtf(var + LN_EPS);
        }
        __syncthreads();
        float gg = g1[t127], bb = be1[t127];
#pragma unroll
        for (int r = 0; r < 32; ++r) {
          float v = (acc[r] - lnp[r][0]) * lnp[r][1];
          v = fmaf(v, gg, bb);
          bufT[t127 * 36 + r] = fmaxf(v, 0.f);
        }
        __syncthreads();
      }
      // ---- layer 2 ----
      {
        float bias = b2[t127];
#pragma unroll
        for (int r = 0; r < 32; ++r) acc[r] = bias;
        for (int i = 0; i < D1; ++i) {
          float w = W2[i * D2 + t127];
          const float* hr = &bufT[i * 36];
#pragma unroll
          for (int r = 0; r < 32; ++r) acc[r] = fmaf(hr[r], w, acc[r]);
        }
      }
      {
        __syncthreads();
#pragma unroll
        for (int r = 0; r < 32; ++r) bufT[t127 * 36 + r] = acc[r];
        __syncthreads();
        {
          int r = t127 & 31, seg = t127 >> 5;
          float s = 0.f, ss = 0.f;
#pragma unroll
          for (int u = 0; u < 32; ++u) {
            float v = bufT[(seg * 32 + u) * 36 + r];
            s += v; ss = fmaf(v, v, ss);
          }
          red[r][seg][0] = s; red[r][seg][1] = ss;
        }
        __syncthreads();
        if (t127 < 32) {
          float s  = red[t127][0][0] + red[t127][1][0] + red[t127][2][0] + red[t127][3][0];
          float ss = red[t127][0][1] + red[t127][1][1] + red[t127][2][1] + red[t127][3][1];
          float mm = s * (1.0f / D2);
          float var = ss * (1.0f / D2) - mm * mm;
          lnp[t127][0] = mm;
          lnp[t127][1] = rsqrtf(var + LN_EPS);
        }
        __syncthreads();
        float gg = g2[t127], bb = be2[t127];
#pragma unroll
        for (int r = 0; r < 32; ++r) {
          float v = (acc[r] - lnp[r][0]) * lnp[r][1];
          v = fmaf(v, gg, bb);
          bufT[t127 * 36 + r] = fmaxf(v, 0.f);
        }
        __syncthreads();
      }
      // ---- layer 3 + max over k: two 32-reg passes ----
      float* of = out + (size_t)g * D3;
#pragma unroll 1
      for (int half = 0; half < 2; ++half) {
        int col = t127 + (half << 7);
        float a[32];
        float bias = b3[col];
#pragma unroll
        for (int r = 0; r < 32; ++r) a[r] = bias;
        for (int i = 0; i < D2; ++i) {
          float w = W3[i * D3 + col];
          const float* hr = &bufT[i * 36];
#pragma unroll
          for (int r = 0; r < 32; ++r) a[r] = fmaf(hr[r], w, a[r]);
        }
        float m0 = a[0];
#pragma unroll
        for (int r = 1; r < 32; ++r) m0 = fmaxf(m0, a[r]);
        of[col] = m0;
      }
      __syncthreads();   // sub-blocks done before LDS reuse by next item
    }
  }
#undef PROG_AT
#undef KCNT_AT
#undef KFLAG_AT
}

// ---------------------------------------------------------------------------
extern "C" void kernel_launch(void* const* d_in, const int* in_sizes, int n_in,
                              void* d_out, int out_size, void* d_ws, size_t ws_size,
                              hipStream_t stream) {
  const float* xyz      = (const float*)d_in[0];
  const float* features = (const float*)d_in[1];
  const float* W1  = (const float*)d_in[2];
  const float* b1  = (const float*)d_in[3];
  const float* g1  = (const float*)d_in[4];
  const float* be1 = (const float*)d_in[5];
  const float* W2  = (const float*)d_in[6];
  const float* b2  = (const float*)d_in[7];
  const float* g2  = (const float*)d_in[8];
  const float* be2 = (const float*)d_in[9];
  const float* W3  = (const float*)d_in[10];
  const float* b3  = (const float*)d_in[11];

  float* new_xyz  = (float*)d_out;
  float* new_feat = (float*)d_out + (size_t)BATCH * NPOINT * 3;

  int* knn_idx = (int*)d_ws;                                    // 2 MB
  unsigned char* ctl = (unsigned char*)d_ws +
                       (size_t)BATCH * NPOINT * NSAMPLE * 4;

  hipMemsetAsync(ctl, 0, CTL_BYTES, stream);
  fused_kernel<<<dim3(NBLOCKS), dim3(1024), 0, stream>>>(
      xyz, features, W1, b1, g1, be1, W2, b2, g2, be2, W3, b3,
      knn_idx, ctl, new_xyz, new_feat);
}

// Round 19
// 4377.273 us; speedup vs baseline: 1.2955x; 1.1043x over previous
//
#include <hip/hip_runtime.h>
#include <cstdint>
#include <cstddef>

#define BATCH   8
#define NPTS    16384
#define CFEAT   64
#define NPOINT  2048
#define NSAMPLE 32
#define DIN     124
#define D1      128
#define D2      128
#define D3      256
#define LN_EPS  1e-5f

#define NFPS      8
#define NBLOCKS   256
#define KNN_ITEMS 128                   // 128 centroids per item (16 waves x 8)
#define MLP_ITEMS 2048                  // 8 centroids per item
#define TOT_ITEMS (KNN_ITEMS + MLP_ITEMS)

#define SB_BYTES   19872                // per-mlp-sub-block LDS region
#define SMEM_BYTES (8 * SB_BYTES)       // 158976 <= 160 KiB -> 1 block/CU

// control block layout (byte offsets; every sync word on its OWN 64B line)
#define CTL_QHEAD   0
#define CTL_PROG    1024    // prog[b]  at 1024 + b*256
#define CTL_KCNT    4096    // kcnt[k]  at 4096 + k*64
#define CTL_KFLAG   16384   // kflag[k] at 16384 + k*64
#define CTL_BYTES   32768

#define PTS16(F) F(0) F(1) F(2) F(3) F(4) F(5) F(6) F(7) \
                 F(8) F(9) F(10) F(11) F(12) F(13) F(14) F(15)

// sorted point storage (module BSS; r8/r18-proven pattern)
__device__ float          g_sx[BATCH][NPTS];
__device__ float          g_sy[BATCH][NPTS];
__device__ float          g_sz[BATCH][NPTS];
__device__ unsigned short g_so[BATCH][NPTS];   // original index

// ---------------------------------------------------------------------------
// Fused producer/consumer kernel (r19 = r18 with a 2-barrier FPS step).
// FPS blocks 0..7: Morton-sorted points, wave-bbox skip (r18-proven).
// Step tail restructured: after B2 every thread decodes the winner's
// ORIGINAL index from s_packed and loads its coords from global X
// (broadcast, bit-identical bytes) -- no owner phase, no third barrier.
// s_packed double-buffered by step parity; off-slot reset sits post-B1
// (barrier-separated from last readers and next writers).
// Workers (blocks 8..255): FIFO queue, 128 knn then 2048 mlp items
// (byte-identical to r14..r18). Exact reference f32 math everywhere.
// ---------------------------------------------------------------------------
__attribute__((amdgpu_waves_per_eu(4, 4)))
__global__ __launch_bounds__(1024) void fused_kernel(
    const float* __restrict__ xyz, const float* __restrict__ features,
    const float* __restrict__ W1, const float* __restrict__ b1,
    const float* __restrict__ g1, const float* __restrict__ be1,
    const float* __restrict__ W2, const float* __restrict__ b2,
    const float* __restrict__ g2, const float* __restrict__ be2,
    const float* __restrict__ W3, const float* __restrict__ b3,
    int* __restrict__ knn_idx, unsigned char* __restrict__ ctl,
    float* __restrict__ new_xyz, float* __restrict__ out)
{
  __shared__ __align__(16) unsigned char smem[SMEM_BYTES];
  __shared__ unsigned s_item;
  const int t = threadIdx.x;

  unsigned* qhead = (unsigned*)(ctl + CTL_QHEAD);
#define PROG_AT(b)  ((int*)(ctl + CTL_PROG + (b) * 256))
#define KCNT_AT(k)  ((unsigned*)(ctl + CTL_KCNT + (k) * 64))
#define KFLAG_AT(k) ((unsigned*)(ctl + CTL_KFLAG + (k) * 64))

  // ========================= FPS role (blocks 0..7) =========================
  if (blockIdx.x < NFPS) {
    const int b = blockIdx.x;
    const float* X = xyz + (size_t)b * NPTS * 3;

    float4 (*s_mind4)[1024] = reinterpret_cast<float4(*)[1024]>(smem);
    unsigned short* s_oidx  = (unsigned short*)(smem + 65536);   // [k<<10 | t]
    float* wvv              = (float*)(smem + 98304);
    unsigned long long* s_packed = (unsigned long long*)(smem + 98368); // [2]
    float (*wbb)[6]         = (float(*)[6])(smem + 98496);       // per-wave bbox
    float* gpar             = (float*)(smem + 98944);            // lo xyz, iscale xyz
    unsigned* cstart        = (unsigned*)(smem + 99008);         // [513]
    unsigned* ccur          = (unsigned*)(smem + 101120);        // [512]
    float (*redbuf)[6]      = (float(*)[6])(smem + 103168);

#define DECLP(i) float px##i, py##i, pz##i;
    PTS16(DECLP)
#undef DECLP
    // ---- load original strided layout ----
#define LOADP(i) { int j = t + (i << 10);  \
    px##i = X[3 * j + 0];                  \
    py##i = X[3 * j + 1];                  \
    pz##i = X[3 * j + 2]; }
    PTS16(LOADP)
#undef LOADP

    // ---- global bbox reduce (for cell grid) ----
    {
      float mnx = px0, mxx = px0, mny = py0, mxy = py0, mnz = pz0, mxz = pz0;
#define BB(i) { mnx = fminf(mnx, px##i); mxx = fmaxf(mxx, px##i);  \
                mny = fminf(mny, py##i); mxy = fmaxf(mxy, py##i);  \
                mnz = fminf(mnz, pz##i); mxz = fmaxf(mxz, pz##i); }
      PTS16(BB)
#undef BB
#pragma unroll
      for (int off = 32; off >= 1; off >>= 1) {
        mnx = fminf(mnx, __shfl_xor(mnx, off)); mxx = fmaxf(mxx, __shfl_xor(mxx, off));
        mny = fminf(mny, __shfl_xor(mny, off)); mxy = fmaxf(mxy, __shfl_xor(mxy, off));
        mnz = fminf(mnz, __shfl_xor(mnz, off)); mxz = fmaxf(mxz, __shfl_xor(mxz, off));
      }
      if ((t & 63) == 0) {
        int w = t >> 6;
        redbuf[w][0] = mnx; redbuf[w][1] = mxx; redbuf[w][2] = mny;
        redbuf[w][3] = mxy; redbuf[w][4] = mnz; redbuf[w][5] = mxz;
      }
      if (t < 513) cstart[t] = 0;
      __syncthreads();
      if (t == 0) {
        float a0 = redbuf[0][0], a1 = redbuf[0][1], a2 = redbuf[0][2];
        float a3 = redbuf[0][3], a4 = redbuf[0][4], a5 = redbuf[0][5];
        for (int w = 1; w < 16; ++w) {
          a0 = fminf(a0, redbuf[w][0]); a1 = fmaxf(a1, redbuf[w][1]);
          a2 = fminf(a2, redbuf[w][2]); a3 = fmaxf(a3, redbuf[w][3]);
          a4 = fminf(a4, redbuf[w][4]); a5 = fmaxf(a5, redbuf[w][5]);
        }
        float rx = a1 - a0, ry = a3 - a2, rz = a5 - a4;
        gpar[0] = a0; gpar[1] = a2; gpar[2] = a4;
        gpar[3] = (rx > 1e-20f) ? 8.0f / rx : 0.f;
        gpar[4] = (ry > 1e-20f) ? 8.0f / ry : 0.f;
        gpar[5] = (rz > 1e-20f) ? 8.0f / rz : 0.f;
        s_packed[0] = 0ull; s_packed[1] = 0ull;
      }
      __syncthreads();
    }

    // Morton cell id (3x3-bit interleave)
#define CELLM(x, y, z) ({                                              \
    int ix_ = (int)((x - gpar[0]) * gpar[3]);                          \
    int iy_ = (int)((y - gpar[1]) * gpar[4]);                          \
    int iz_ = (int)((z - gpar[2]) * gpar[5]);                          \
    ix_ = ix_ < 0 ? 0 : (ix_ > 7 ? 7 : ix_);                           \
    iy_ = iy_ < 0 ? 0 : (iy_ > 7 ? 7 : iy_);                           \
    iz_ = iz_ < 0 ? 0 : (iz_ > 7 ? 7 : iz_);                           \
    (((ix_ & 1) | ((ix_ & 2) << 2) | ((ix_ & 4) << 4))                 \
     | (((iy_ & 1) | ((iy_ & 2) << 2) | ((iy_ & 4) << 4)) << 1)        \
     | (((iz_ & 1) | ((iz_ & 2) << 2) | ((iz_ & 4) << 4)) << 2)); })

    // ---- histogram ----
#define CIDK(i) { int m_ = CELLM(px##i, py##i, pz##i); \
    atomicAdd(&cstart[m_ + 1], 1u); }
    PTS16(CIDK)
#undef CIDK
    __syncthreads();

    // ---- prefix scan (wave 0; r8-proven) ----
    if (t < 64) {
      unsigned v[8], p[8];
      unsigned run = 0;
#pragma unroll
      for (int j = 0; j < 8; ++j) { v[j] = cstart[t * 8 + 1 + j]; run += v[j]; p[j] = run; }
      unsigned tot = run;
#pragma unroll
      for (int off = 1; off < 64; off <<= 1) {
        unsigned u = __shfl_up(run, off);
        if ((t & 63) >= off) run += u;
      }
      unsigned excl = run - tot;
      if (t == 0) cstart[0] = 0;
#pragma unroll
      for (int j = 0; j < 8; ++j) cstart[t * 8 + 1 + j] = excl + p[j];
    }
    __syncthreads();
    if (t < 512) ccur[t] = cstart[t];
    __syncthreads();

    // ---- scatter to global (sorted SoA) ----
#define SCATK(i) { int j = t + (i << 10);                              \
    int m_ = CELLM(px##i, py##i, pz##i);                               \
    unsigned dst = atomicAdd(&ccur[m_], 1u);                           \
    g_sx[b][dst] = px##i; g_sy[b][dst] = py##i; g_sz[b][dst] = pz##i;  \
    g_so[b][dst] = (unsigned short)j; }
    PTS16(SCATK)
#undef SCATK
#undef CELLM
    __syncthreads();

    // ---- reload sorted (thread t owns [t*16, t*16+16)), thread bbox ----
    float tlx = 1e30f, thx = -1e30f, tly = 1e30f, thy = -1e30f,
          tlz = 1e30f, thz = -1e30f;
#define RELK(i) { int p_ = (t << 4) + i;                               \
    px##i = g_sx[b][p_]; py##i = g_sy[b][p_]; pz##i = g_sz[b][p_];     \
    s_oidx[(i << 10) + t] = g_so[b][p_];                               \
    tlx = fminf(tlx, px##i); thx = fmaxf(thx, px##i);                  \
    tly = fminf(tly, py##i); thy = fmaxf(thy, py##i);                  \
    tlz = fminf(tlz, pz##i); thz = fmaxf(thz, pz##i); }
    PTS16(RELK)
#undef RELK
    s_mind4[0][t] = make_float4(1e10f, 1e10f, 1e10f, 1e10f);
    s_mind4[1][t] = make_float4(1e10f, 1e10f, 1e10f, 1e10f);
    s_mind4[2][t] = make_float4(1e10f, 1e10f, 1e10f, 1e10f);
    s_mind4[3][t] = make_float4(1e10f, 1e10f, 1e10f, 1e10f);

    // ---- wave bbox ----
#pragma unroll
    for (int off = 32; off >= 1; off >>= 1) {
      tlx = fminf(tlx, __shfl_xor(tlx, off)); thx = fmaxf(thx, __shfl_xor(thx, off));
      tly = fminf(tly, __shfl_xor(tly, off)); thy = fmaxf(thy, __shfl_xor(thy, off));
      tlz = fminf(tlz, __shfl_xor(tlz, off)); thz = fmaxf(thz, __shfl_xor(thz, off));
    }
    if ((t & 63) == 0) {
      int w = t >> 6;
      wbb[w][0] = tlx; wbb[w][1] = thx; wbb[w][2] = tly;
      wbb[w][3] = thy; wbb[w][4] = tlz; wbb[w][5] = thz;
    }

    float mybest = -1.0f;
    float wvmax  = 1e10f;
    float cx = X[0], cy = X[1], cz = X[2];   // start centroid (broadcast)
    __syncthreads();

    // ======================= main FPS loop (2 barriers) ======================
    for (int s = 0; s < NPOINT; ++s) {
      if (t == 0) {
        float* o = new_xyz + ((size_t)b * NPOINT + s) * 3;
        o[0] = cx; o[1] = cy; o[2] = cz;
        if (((s + 1) & 15) == 0) {   // publish every 16 steps (incl. s=2047)
          __builtin_amdgcn_fence(__ATOMIC_RELEASE, "agent");
          __hip_atomic_store(PROG_AT(b), s + 1, __ATOMIC_RELAXED,
                             __HIP_MEMORY_SCOPE_AGENT);
        }
      }
      if (s == NPOINT - 1) break;

      // pin coords (blocks spill/remat)
      asm volatile("" : "+v"(px0), "+v"(px1), "+v"(px2), "+v"(px3),
                        "+v"(px4), "+v"(px5), "+v"(px6), "+v"(px7),
                        "+v"(px8), "+v"(px9), "+v"(px10), "+v"(px11),
                        "+v"(px12), "+v"(px13), "+v"(px14), "+v"(px15));
      asm volatile("" : "+v"(py0), "+v"(py1), "+v"(py2), "+v"(py3),
                        "+v"(py4), "+v"(py5), "+v"(py6), "+v"(py7),
                        "+v"(py8), "+v"(py9), "+v"(py10), "+v"(py11),
                        "+v"(py12), "+v"(py13), "+v"(py14), "+v"(py15));
      asm volatile("" : "+v"(pz0), "+v"(pz1), "+v"(pz2), "+v"(pz3),
                        "+v"(pz4), "+v"(pz5), "+v"(pz6), "+v"(pz7),
                        "+v"(pz8), "+v"(pz9), "+v"(pz10), "+v"(pz11),
                        "+v"(pz12), "+v"(pz13), "+v"(pz14), "+v"(pz15));

      // ---- wave-uniform skip test + conditional exact update ----
      {
        const int w = t >> 6;
        float lox = wbb[w][0], hix = wbb[w][1];
        float loy = wbb[w][2], hiy = wbb[w][3];
        float loz = wbb[w][4], hiz = wbb[w][5];
        float ddx = fmaxf(fmaxf(lox - cx, cx - hix), 0.f);
        float ddy = fmaxf(fmaxf(loy - cy, cy - hiy), 0.f);
        float ddz = fmaxf(fmaxf(loz - cz, cz - hiz), 0.f);
        float dlb2 = ddx * ddx + ddy * ddy + ddz * ddz;
        if (dlb2 < wvmax * 1.0001f) {
          mybest = -1.0f;
#define DIST(i) ({                                                       \
    float dx_ = __fsub_rn(px##i, cx);                                    \
    float dy_ = __fsub_rn(py##i, cy);                                    \
    float dz_ = __fsub_rn(pz##i, cz);                                    \
    __fadd_rn(__fadd_rn(__fmul_rn(dx_, dx_), __fmul_rn(dy_, dy_)),       \
              __fmul_rn(dz_, dz_)); })
#define PACKSTEP(p, i0, i1, i2, i3) {                                    \
    float4 dv = s_mind4[p][t];                                           \
    dv.x = fminf(dv.x, DIST(i0));                                        \
    dv.y = fminf(dv.y, DIST(i1));                                        \
    dv.z = fminf(dv.z, DIST(i2));                                        \
    dv.w = fminf(dv.w, DIST(i3));                                        \
    s_mind4[p][t] = dv;                                                  \
    mybest = fmaxf(mybest, fmaxf(fmaxf(dv.x, dv.y), fmaxf(dv.z, dv.w))); }
          PACKSTEP(0, 0, 1, 2, 3)
          PACKSTEP(1, 4, 5, 6, 7)
          PACKSTEP(2, 8, 9, 10, 11)
          PACKSTEP(3, 12, 13, 14, 15)
#undef PACKSTEP
#undef DIST
          float wmax = mybest;
#pragma unroll
          for (int off = 32; off >= 1; off >>= 1)
            wmax = fmaxf(wmax, __shfl_xor(wmax, off));
          wvmax = wmax;
          if ((t & 63) == 0) wvv[w] = wmax;
        }
      }
      __syncthreads();   // B1

      if (t == 0) s_packed[(s & 1) ^ 1] = 0ull;   // prep next step's slot

      // stage 2 (redundant, f32): 4x b128 broadcast + max tree
      float4 v0 = *(const float4*)&wvv[0];
      float4 v1 = *(const float4*)&wvv[4];
      float4 v2 = *(const float4*)&wvv[8];
      float4 v3 = *(const float4*)&wvv[12];
      float g = fmaxf(
          fmaxf(fmaxf(fmaxf(v0.x, v0.y), fmaxf(v0.z, v0.w)),
                fmaxf(fmaxf(v1.x, v1.y), fmaxf(v1.z, v1.w))),
          fmaxf(fmaxf(fmaxf(v2.x, v2.y), fmaxf(v2.z, v2.w)),
                fmaxf(fmaxf(v3.x, v3.y), fmaxf(v3.z, v3.w))));

      // winners (bit-exact; rare): smallest ORIGINAL index in-thread,
      // u64 atomicMax resolves cross-thread (value desc, orig asc)
      if (mybest == g) {
        unsigned bo = 0xFFFFu;
#pragma unroll
        for (int p = 0; p < 4; ++p) {
          float4 dv = s_mind4[p][t];
          { unsigned o = s_oidx[((4 * p + 0) << 10) + t];
            if (dv.x == g && o < bo) bo = o; }
          { unsigned o = s_oidx[((4 * p + 1) << 10) + t];
            if (dv.y == g && o < bo) bo = o; }
          { unsigned o = s_oidx[((4 * p + 2) << 10) + t];
            if (dv.z == g && o < bo) bo = o; }
          { unsigned o = s_oidx[((4 * p + 3) << 10) + t];
            if (dv.w == g && o < bo) bo = o; }
        }
        unsigned long long pk =
            ((unsigned long long)__float_as_uint(g) << 32) |
            (unsigned)(~bo & 0xFFFFu);
        atomicMax(&s_packed[s & 1], pk);
      }
      __syncthreads();   // B2

      // all threads decode winner's ORIGINAL index; load coords from global
      unsigned long long gp = s_packed[s & 1];
      int orig = (int)((~(unsigned)(gp & 0xffffffffull)) & 0xFFFFu);
      const float* Wp = X + 3 * (size_t)orig;   // broadcast, L1/L2-resident
      cx = Wp[0]; cy = Wp[1]; cz = Wp[2];
    }
    return;
  }

  // ========================= worker role (blocks 8..255) ====================
  for (;;) {
    __syncthreads();
    if (t == 0)
      s_item = __hip_atomic_fetch_add(qhead, 1u, __ATOMIC_RELAXED,
                                      __HIP_MEMORY_SCOPE_AGENT);
    __syncthreads();
    unsigned item = s_item;
    if (item >= TOT_ITEMS) return;

    if (item < KNN_ITEMS) {
      // ---------------- knn item: 128 centroids, 16 waves x 8 --------------
      const int k = (int)item;
      const int b = k >> 4;                    // 16 chunks per batch
      const int chunk = k & 15;
      const int lane = t & 63;
      const int wid  = t >> 6;
      const int gidbase = b * NPOINT + chunk * 128 + wid * 8;
      const int need = chunk * 128 + wid * 8 + 8;
      const float* X = xyz + (size_t)b * NPTS * 3;

      if (lane == 0) {
        while (__hip_atomic_load(PROG_AT(b), __ATOMIC_RELAXED,
                                 __HIP_MEMORY_SCOPE_AGENT) < need)
          __builtin_amdgcn_s_sleep(64);
      }
      __builtin_amdgcn_fence(__ATOMIC_ACQUIRE, "agent");

      float cx[8], cy[8], cz[8];
#pragma unroll
      for (int c = 0; c < 8; ++c) {
        const float* p = new_xyz + (size_t)(gidbase + c) * 3;
        cx[c] = p[0]; cy[c] = p[1]; cz[c] = p[2];
      }
      float qd[8]; int qi[8]; float T[8];
#pragma unroll
      for (int c = 0; c < 8; ++c) { qd[c] = 3.4e38f; qi[c] = 0; T[c] = 3.4e38f; }

      for (int base = 0; base < NPTS; base += 64) {
        const int j = base + lane;
        const float x = X[3 * j + 0];
        const float y = X[3 * j + 1];
        const float z = X[3 * j + 2];
#pragma unroll
        for (int c = 0; c < 8; ++c) {
          float dx = __fsub_rn(x, cx[c]);
          float dy = __fsub_rn(y, cy[c]);
          float dz = __fsub_rn(z, cz[c]);
          float v  = __fadd_rn(__fadd_rn(__fmul_rn(dx, dx), __fmul_rn(dy, dy)),
                               __fmul_rn(dz, dz));
          unsigned long long m = __ballot(v < T[c]);
          while (m) {
            int bit = __ffsll(m) - 1;
            m &= m - 1;
            float vb = __shfl(v, bit);
            if (vb < T[c]) {
              int   jb = base + bit;
              float du = __shfl_up(qd[c], 1);
              int   iu = __shfl_up(qi[c], 1);
              bool c2 = (lane > 0) && (vb < du);
              bool c1 = vb < qd[c];
              qd[c] = c2 ? du : (c1 ? vb : qd[c]);
              qi[c] = c2 ? iu : (c1 ? jb : qi[c]);
              T[c] = __shfl(qd[c], 31);
            }
          }
        }
      }
#pragma unroll
      for (int c = 0; c < 8; ++c) {
        if (lane < 32) knn_idx[(size_t)(gidbase + c) * NSAMPLE + lane] = qi[c];
      }
      __builtin_amdgcn_fence(__ATOMIC_RELEASE, "agent");
      if (lane == 0) {
        unsigned d = __hip_atomic_fetch_add(KCNT_AT(k), 1u, __ATOMIC_ACQ_REL,
                                            __HIP_MEMORY_SCOPE_AGENT);
        if (d == 15u)
          __hip_atomic_store(KFLAG_AT(k), 1u, __ATOMIC_RELEASE,
                             __HIP_MEMORY_SCOPE_AGENT);
      }
    } else {
      // ---------------- mlp item: 8 centroids, 8 x 128-thr sub-blocks ------
      const int m = (int)(item - KNN_ITEMS);
      const int gbase = m << 3;
      const int b = gbase / NPOINT;
      const int sb = t >> 7;
      const int t127 = t & 127;
      const int g = gbase + sb;

      if (t == 0) {
        while (__hip_atomic_load(KFLAG_AT(m >> 4), __ATOMIC_RELAXED,
                                 __HIP_MEMORY_SCOPE_AGENT) == 0u)
          __builtin_amdgcn_s_sleep(64);
      }
      __syncthreads();
      __builtin_amdgcn_fence(__ATOMIC_ACQUIRE, "agent");

      unsigned char* base_ = smem + sb * SB_BYTES;
      float* bufT = (float*)base_;                         // 128*36 floats
      float (*red)[4][2] = (float(*)[4][2])(base_ + 18432);
      float (*lnp)[2]    = (float(*)[2])(base_ + 19456);
      int*   ki          = (int*)(base_ + 19712);
      float* cen         = (float*)(base_ + 19840);

      if (t127 < 32) ki[t127] = knn_idx[(size_t)g * NSAMPLE + t127];
      if (t127 < 3)  cen[t127] = new_xyz[(size_t)g * 3 + t127];
      __syncthreads();

      {
        int r = t127 & 31, cs = (t127 >> 5) << 4;
        const float* frow = features + ((size_t)b * NPTS + ki[r]) * CFEAT + cs;
#pragma unroll
        for (int u = 0; u < 4; ++u) {
          float4 f = *(const float4*)(frow + 4 * u);
          bufT[(cs + 4 * u + 0) * 36 + r] = f.x;
          bufT[(cs + 4 * u + 1) * 36 + r] = f.y;
          bufT[(cs + 4 * u + 2) * 36 + r] = f.z;
          bufT[(cs + 4 * u + 3) * 36 + r] = f.w;
        }
      }
      if (t127 < 32) {
        const float* p = xyz + ((size_t)b * NPTS + ki[t127]) * 3;
        float rx = p[0] - cen[0];
        float ry = p[1] - cen[1];
        float rz = p[2] - cen[2];
#pragma unroll
        for (int l = 0; l < 10; ++l) {
          float sc = (float)(1 << l);
          float ax = rx * sc, ay = ry * sc, az = rz * sc;
          int bbi = (64 + l * 6) * 36 + t127;
          bufT[bbi + 0 * 36] = __sinf(ax);
          bufT[bbi + 1 * 36] = __sinf(ay);
          bufT[bbi + 2 * 36] = __sinf(az);
          bufT[bbi + 3 * 36] = __cosf(ax);
          bufT[bbi + 4 * 36] = __cosf(ay);
          bufT[bbi + 5 * 36] = __cosf(az);
        }
      }
      __syncthreads();

      float acc[32];
      // ---- layer 1 ----
      {
        float bias = b1[t127];
#pragma unroll
        for (int r = 0; r < 32; ++r) acc[r] = bias;
        for (int i = 0; i < DIN; ++i) {
          float w = W1[i * D1 + t127];
          const float* hr = &bufT[i * 36];
#pragma unroll
          for (int r = 0; r < 32; ++r) acc[r] = fmaf(hr[r], w, acc[r]);
        }
      }
      {
        __syncthreads();
#pragma unroll
        for (int r = 0; r < 32; ++r) bufT[t127 * 36 + r] = acc[r];
        __syncthreads();
        {
          int r = t127 & 31, seg = t127 >> 5;
          float s = 0.f, ss = 0.f;
#pragma unroll
          for (int u = 0; u < 32; ++u) {
            float v = bufT[(seg * 32 + u) * 36 + r];
            s += v; ss = fmaf(v, v, ss);
          }
          red[r][seg][0] = s; red[r][seg][1] = ss;
        }
        __syncthreads();
        if (t127 < 32) {
          float s  = red[t127][0][0] + red[t127][1][0] + red[t127][2][0] + red[t127][3][0];
          float ss = red[t127][0][1] + red[t127][1][1] + red[t127][2][1] + red[t127][3][1];
          float mm = s * (1.0f / D1);
          float var = ss * (1.0f / D1) - mm * mm;
          lnp[t127][0] = mm;
          lnp[t127][1] = rsqrtf(var + LN_EPS);
        }
        __syncthreads();
        float gg = g1[t127], bb = be1[t127];
#pragma unroll
        for (int r = 0; r < 32; ++r) {
          float v = (acc[r] - lnp[r][0]) * lnp[r][1];
          v = fmaf(v, gg, bb);
          bufT[t127 * 36 + r] = fmaxf(v, 0.f);
        }
        __syncthreads();
      }
      // ---- layer 2 ----
      {
        float bias = b2[t127];
#pragma unroll
        for (int r = 0; r < 32; ++r) acc[r] = bias;
        for (int i = 0; i < D1; ++i) {
          float w = W2[i * D2 + t127];
          const float* hr = &bufT[i * 36];
#pragma unroll
          for (int r = 0; r < 32; ++r) acc[r] = fmaf(hr[r], w, acc[r]);
        }
      }
      {
        __syncthreads();
#pragma unroll
        for (int r = 0; r < 32; ++r) bufT[t127 * 36 + r] = acc[r];
        __syncthreads();
        {
          int r = t127 & 31, seg = t127 >> 5;
          float s = 0.f, ss = 0.f;
#pragma unroll
          for (int u = 0; u < 32; ++u) {
            float v = bufT[(seg * 32 + u) * 36 + r];
            s += v; ss = fmaf(v, v, ss);
          }
          red[r][seg][0] = s; red[r][seg][1] = ss;
        }
        __syncthreads();
        if (t127 < 32) {
          float s  = red[t127][0][0] + red[t127][1][0] + red[t127][2][0] + red[t127][3][0];
          float ss = red[t127][0][1] + red[t127][1][1] + red[t127][2][1] + red[t127][3][1];
          float mm = s * (1.0f / D2);
          float var = ss * (1.0f / D2) - mm * mm;
          lnp[t127][0] = mm;
          lnp[t127][1] = rsqrtf(var + LN_EPS);
        }
        __syncthreads();
        float gg = g2[t127], bb = be2[t127];
#pragma unroll
        for (int r = 0; r < 32; ++r) {
          float v = (acc[r] - lnp[r][0]) * lnp[r][1];
          v = fmaf(v, gg, bb);
          bufT[t127 * 36 + r] = fmaxf(v, 0.f);
        }
        __syncthreads();
      }
      // ---- layer 3 + max over k: two 32-reg passes ----
      float* of = out + (size_t)g * D3;
#pragma unroll 1
      for (int half = 0; half < 2; ++half) {
        int col = t127 + (half << 7);
        float a[32];
        float bias = b3[col];
#pragma unroll
        for (int r = 0; r < 32; ++r) a[r] = bias;
        for (int i = 0; i < D2; ++i) {
          float w = W3[i * D3 + col];
          const float* hr = &bufT[i * 36];
#pragma unroll
          for (int r = 0; r < 32; ++r) a[r] = fmaf(hr[r], w, a[r]);
        }
        float m0 = a[0];
#pragma unroll
        for (int r = 1; r < 32; ++r) m0 = fmaxf(m0, a[r]);
        of[col] = m0;
      }
      __syncthreads();   // sub-blocks done before LDS reuse by next item
    }
  }
#undef PROG_AT
#undef KCNT_AT
#undef KFLAG_AT
}

// ---------------------------------------------------------------------------
extern "C" void kernel_launch(void* const* d_in, const int* in_sizes, int n_in,
                              void* d_out, int out_size, void* d_ws, size_t ws_size,
                              hipStream_t stream) {
  const float* xyz      = (const float*)d_in[0];
  const float* features = (const float*)d_in[1];
  const float* W1  = (const float*)d_in[2];
  const float* b1  = (const float*)d_in[3];
  const float* g1  = (const float*)d_in[4];
  const float* be1 = (const float*)d_in[5];
  const float* W2  = (const float*)d_in[6];
  const float* b2  = (const float*)d_in[7];
  const float* g2  = (const float*)d_in[8];
  const float* be2 = (const float*)d_in[9];
  const float* W3  = (const float*)d_in[10];
  const float* b3  = (const float*)d_in[11];

  float* new_xyz  = (float*)d_out;
  float* new_feat = (float*)d_out + (size_t)BATCH * NPOINT * 3;

  int* knn_idx = (int*)d_ws;                                    // 2 MB
  unsigned char* ctl = (unsigned char*)d_ws +
                       (size_t)BATCH * NPOINT * NSAMPLE * 4;

  hipMemsetAsync(ctl, 0, CTL_BYTES, stream);
  fused_kernel<<<dim3(NBLOCKS), dim3(1024), 0, stream>>>(
      xyz, features, W1, b1, g1, be1, W2, b2, g2, be2, W3, b3,
      knn_idx, ctl, new_xyz, new_feat);
}